// Round 1
// baseline (413.638 us; speedup 1.0000x reference)
//
#include <hip/hip_runtime.h>
#include <math.h>

#define BB 16
#define TT 24
#define NN 2048
#define FF 64
#define BT (BB*TT)        // 384
#define T2 (TT*TT)        // 576
#define NF4 (NN*FF/4)     // 32768 float4 per (b,t) slab

// workspace layout (floats)
#define WS_T1   0
#define WS_RHS  (WS_T1  + BT*FF)       // 24576
#define WS_LHS  (WS_RHS + BT*NN)       // 24576 + 786432
#define WS_SIG  (WS_LHS + BT*NN)
#define WS_AMAT (WS_SIG + BB*T2)

__device__ __forceinline__ float4 f4zero() { return make_float4(0.f,0.f,0.f,0.f); }

// ---------------------------------------------------------------------------
// Kernel 1: read x once; produce
//   t1[bt][f]  = sum_n x[bt][n][f] * U1[n]      (atomicAdd across n-chunks)
//   rhs[bt][n] = sum_f x[bt][n][f] * U3[f]
// grid (BT, 4), block 256. Wave layout: lane = rowgrp*16 + fq;
// fq indexes float4 within a row (F=64 -> 16 float4), rowgrp = 4 rows/wave.
// ---------------------------------------------------------------------------
__global__ __launch_bounds__(256) void k_stage1(
    const float4* __restrict__ x4, const float* __restrict__ U1,
    const float4* __restrict__ U3_4, float* __restrict__ t1,
    float* __restrict__ rhs)
{
    const int bt    = blockIdx.x;
    const int nbase = blockIdx.y * 512;
    const int tid   = threadIdx.x;
    const int wave  = tid >> 6;
    const int lane  = tid & 63;
    const int rowg  = lane >> 4;
    const int fq    = lane & 15;

    const float4 u3 = U3_4[fq];
    float4 t1a = f4zero();
    const float4* xb = x4 + (size_t)bt * NF4;

    for (int i = 0; i < 32; ++i) {
        const int n = nbase + i*16 + wave*4 + rowg;
        const float4 xv = xb[(size_t)n*16 + fq];
        const float u1n = U1[n];
        t1a.x += xv.x*u1n; t1a.y += xv.y*u1n; t1a.z += xv.z*u1n; t1a.w += xv.w*u1n;
        float r = xv.x*u3.x + xv.y*u3.y + xv.z*u3.z + xv.w*u3.w;
        r += __shfl_xor(r, 8);
        r += __shfl_xor(r, 4);
        r += __shfl_xor(r, 2);
        r += __shfl_xor(r, 1);
        if (fq == 0) rhs[(size_t)bt*NN + n] = r;
    }
    // combine the 4 row-groups within the wave (lanes differing in bits 4,5)
    t1a.x += __shfl_xor(t1a.x, 16); t1a.y += __shfl_xor(t1a.y, 16);
    t1a.z += __shfl_xor(t1a.z, 16); t1a.w += __shfl_xor(t1a.w, 16);
    t1a.x += __shfl_xor(t1a.x, 32); t1a.y += __shfl_xor(t1a.y, 32);
    t1a.z += __shfl_xor(t1a.z, 32); t1a.w += __shfl_xor(t1a.w, 32);

    __shared__ float4 red[4][16];
    if (lane < 16) red[wave][lane] = t1a;
    __syncthreads();
    if (tid < 16) {
        const float4 s0 = red[0][tid], s1 = red[1][tid], s2 = red[2][tid], s3 = red[3][tid];
        float4 tot;
        tot.x = s0.x+s1.x+s2.x+s3.x; tot.y = s0.y+s1.y+s2.y+s3.y;
        tot.z = s0.z+s1.z+s2.z+s3.z; tot.w = s0.w+s1.w+s2.w+s3.w;
        float* dst = t1 + (size_t)bt*FF + tid*4;
        atomicAdd(dst+0, tot.x); atomicAdd(dst+1, tot.y);
        atomicAdd(dst+2, tot.z); atomicAdd(dst+3, tot.w);
    }
}

// ---------------------------------------------------------------------------
// Kernel 2: lhs[bt][n] = sum_f t1[bt][f] * U2[n][f]
// grid (8 n-chunks, 12 bt-chunks of 32), block 256 (one n per thread).
// ---------------------------------------------------------------------------
__global__ __launch_bounds__(256) void k_lhs(
    const float4* __restrict__ t1_4, const float4* __restrict__ U2_4,
    float* __restrict__ lhs)
{
    const int tid = threadIdx.x;
    const int n   = blockIdx.x*256 + tid;
    const int btb = blockIdx.y*32;

    __shared__ float4 t1s[32*16];   // 32 bt rows x 16 float4
    t1s[tid]       = t1_4[(size_t)btb*16 + tid];
    t1s[tid + 256] = t1_4[(size_t)btb*16 + tid + 256];
    __syncthreads();

    float4 u2r[16];
    #pragma unroll
    for (int k = 0; k < 16; ++k) u2r[k] = U2_4[(size_t)n*16 + k];

    for (int bl = 0; bl < 32; ++bl) {
        float acc = 0.f;
        #pragma unroll
        for (int k = 0; k < 16; ++k) {
            const float4 tv = t1s[bl*16 + k];   // uniform -> LDS broadcast
            acc += u2r[k].x*tv.x + u2r[k].y*tv.y + u2r[k].z*tv.z + u2r[k].w*tv.w;
        }
        lhs[(size_t)(btb+bl)*NN + n] = acc;
    }
}

// ---------------------------------------------------------------------------
// Kernel 3: sig[b][i][j] = sigmoid( dot(lhs[b,i,:], rhs[b,j,:]) + be[i][j] )
// one wave per (b,i,j); grid 2304 x block 256 (4 waves).
// ---------------------------------------------------------------------------
__global__ __launch_bounds__(256) void k_prod(
    const float4* __restrict__ lhs4, const float4* __restrict__ rhs4,
    const float* __restrict__ be, float* __restrict__ sig)
{
    const int tid  = threadIdx.x;
    const int wave = tid >> 6, lane = tid & 63;
    const int gw   = blockIdx.x*4 + wave;          // 0 .. B*T2-1
    const int b    = gw / T2;
    const int rem  = gw % T2;
    const int i    = rem / TT;
    const int j    = rem % TT;

    const float4* L = lhs4 + (size_t)(b*TT + i)*(NN/4);
    const float4* R = rhs4 + (size_t)(b*TT + j)*(NN/4);
    float acc = 0.f;
    for (int k = lane; k < NN/4; k += 64) {
        const float4 l = L[k], r = R[k];
        acc += l.x*r.x + l.y*r.y + l.z*r.z + l.w*r.w;
    }
    #pragma unroll
    for (int m = 32; m >= 1; m >>= 1) acc += __shfl_xor(acc, m);
    if (lane == 0) {
        const float p = acc + be[i*TT + j];
        sig[(size_t)(b*TT + i)*TT + j] = 1.0f / (1.0f + expf(-p));
    }
}

// ---------------------------------------------------------------------------
// Kernel 4: E[b][t][r] = sum_s Ve[t][s]*sig[b][s][r]; A = softmax over t.
// one block per b, 576 threads (t = tid/24, r = tid%24).
// ---------------------------------------------------------------------------
__global__ __launch_bounds__(576) void k_softmax(
    const float* __restrict__ sig, const float* __restrict__ Ve,
    float* __restrict__ Amat)
{
    const int b = blockIdx.x, tid = threadIdx.x;
    __shared__ float sigL[T2], VeL[T2], EL[T2], eL[T2];
    sigL[tid] = sig[(size_t)b*T2 + tid];
    VeL[tid]  = Ve[tid];
    __syncthreads();

    const int t = tid / TT, r = tid % TT;
    float E = 0.f;
    #pragma unroll
    for (int s = 0; s < TT; ++s) E += VeL[t*TT + s] * sigL[s*TT + r];
    EL[tid] = E;
    __syncthreads();

    float m = -1e30f;
    for (int tt = 0; tt < TT; ++tt) m = fmaxf(m, EL[tt*TT + r]);
    const float e = expf(E - m);
    eL[tid] = e;
    __syncthreads();

    float ssum = 0.f;
    for (int tt = 0; tt < TT; ++tt) ssum += eL[tt*TT + r];
    Amat[(size_t)b*T2 + tid] = e / ssum;
}

// ---------------------------------------------------------------------------
// Kernel 5: out[b][s][n][f] = sum_t x[b][t][n][f] * A[b][t][s]
// grid (128, B), block 256; one float4 of (n,f) per thread, 24 accumulators.
// ---------------------------------------------------------------------------
__global__ __launch_bounds__(256) void k_out(
    const float4* __restrict__ x4, const float4* __restrict__ Amat4,
    float4* __restrict__ out4)
{
    const int b   = blockIdx.y;
    const int idx = blockIdx.x*256 + threadIdx.x;    // 0 .. NF4-1

    __shared__ float4 A4[TT*6];                      // 24 rows x 6 float4
    if (threadIdx.x < TT*6) A4[threadIdx.x] = Amat4[(size_t)b*TT*6 + threadIdx.x];
    __syncthreads();

    const float4* xb = x4 + (size_t)b*TT*NF4;
    float4 acc[TT];
    #pragma unroll
    for (int s = 0; s < TT; ++s) acc[s] = f4zero();

    for (int t = 0; t < TT; ++t) {
        const float4 xv = xb[(size_t)t*NF4 + idx];
        #pragma unroll
        for (int sq = 0; sq < 6; ++sq) {
            const float4 a = A4[t*6 + sq];           // A[t][4sq..4sq+3]
            acc[4*sq+0].x += xv.x*a.x; acc[4*sq+0].y += xv.y*a.x;
            acc[4*sq+0].z += xv.z*a.x; acc[4*sq+0].w += xv.w*a.x;
            acc[4*sq+1].x += xv.x*a.y; acc[4*sq+1].y += xv.y*a.y;
            acc[4*sq+1].z += xv.z*a.y; acc[4*sq+1].w += xv.w*a.y;
            acc[4*sq+2].x += xv.x*a.z; acc[4*sq+2].y += xv.y*a.z;
            acc[4*sq+2].z += xv.z*a.z; acc[4*sq+2].w += xv.w*a.z;
            acc[4*sq+3].x += xv.x*a.w; acc[4*sq+3].y += xv.y*a.w;
            acc[4*sq+3].z += xv.z*a.w; acc[4*sq+3].w += xv.w*a.w;
        }
    }
    float4* ob = out4 + (size_t)b*TT*NF4;
    #pragma unroll
    for (int s = 0; s < TT; ++s) ob[(size_t)s*NF4 + idx] = acc[s];
}

// ---------------------------------------------------------------------------
extern "C" void kernel_launch(void* const* d_in, const int* in_sizes, int n_in,
                              void* d_out, int out_size, void* d_ws, size_t ws_size,
                              hipStream_t stream)
{
    const float* x  = (const float*)d_in[0];
    const float* U1 = (const float*)d_in[1];
    const float* U2 = (const float*)d_in[2];
    const float* U3 = (const float*)d_in[3];
    const float* be = (const float*)d_in[4];
    const float* Ve = (const float*)d_in[5];

    float* ws  = (float*)d_ws;
    float* t1  = ws + WS_T1;
    float* rhs = ws + WS_RHS;
    float* lhs = ws + WS_LHS;
    float* sg  = ws + WS_SIG;
    float* Am  = ws + WS_AMAT;

    // t1 is accumulated with atomics; zero it every call (ws is re-poisoned).
    hipMemsetAsync(t1, 0, (size_t)BT*FF*sizeof(float), stream);

    k_stage1<<<dim3(BT, 4), 256, 0, stream>>>(
        (const float4*)x, U1, (const float4*)U3, t1, rhs);
    k_lhs<<<dim3(8, 12), 256, 0, stream>>>(
        (const float4*)t1, (const float4*)U2, lhs);
    k_prod<<<dim3((BB*T2)/4), 256, 0, stream>>>(
        (const float4*)lhs, (const float4*)rhs, be, sg);
    k_softmax<<<dim3(BB), 576, 0, stream>>>(sg, Ve, Am);
    k_out<<<dim3(NF4/256, BB), 256, 0, stream>>>(
        (const float4*)x, (const float4*)Am, (float4*)d_out);
}